// Round 10
// baseline (547.923 us; speedup 1.0000x reference)
//
#include <hip/hip_runtime.h>
#include <hip/hip_bf16.h>

#define NPOS   100
#define BATCH  1024
#define DIN    384
#define DOUT   384
#define XROW   (NPOS * DIN)      // 38400 floats, batch-dim stride of x and out
#define WSLICE (DIN * DOUT)

#define BM 256                   // batch rows per block
#define BN 384                   // FULL d_out -> x read exactly once
#define BK 32
#define NK (DIN / BK)            // 12 K-steps
#define PA 40                    // A pitch (shorts): 80B rows (R6-proven)
#define PBT 392                  // B natural-layout pitch (shorts): 784B k-rows
#define ASZ (BM * PA)            // 10240 shorts per A buffer
#define BSZ (BK * PBT)           // 12544 shorts per B buffer
#define LDS_BYTES ((2 * ASZ + 2 * BSZ) * 2)   // 91,136 B

typedef __attribute__((ext_vector_type(8))) short bf16x8;
typedef __attribute__((ext_vector_type(16))) float f32x16;

__device__ __forceinline__ unsigned f2bfu(float f) {
  return (unsigned)__builtin_bit_cast(unsigned short, __float2bfloat16(f));
}
__device__ __forceinline__ unsigned pack2(float a, float b) {
  return f2bfu(a) | (f2bfu(b) << 16);
}

// ds ops visible, vmcnt NOT drained (global prefetch survives the barrier)
__device__ __forceinline__ void barrier_nodrain() {
  asm volatile("s_waitcnt lgkmcnt(0)" ::: "memory");
  __builtin_amdgcn_s_barrier();
}

__global__ __launch_bounds__(512, 1) void nlinear_kernel(
    const float* __restrict__ x, const float* __restrict__ w,
    const float* __restrict__ bias, float* __restrict__ out)
{
  extern __shared__ short smem[];
  short* lA = smem;                 // [2][256][PA]  A tile, bf16 (R6 layout)
  short* lB = smem + 2 * ASZ;       // [2][32][PBT]  B chunk, natural [k][o]

  const int tid  = threadIdx.x;
  const int lane = tid & 63;
  const int wave = tid >> 6;        // 8 waves: 2m x 4n
  const int wm   = wave >> 2;       // 0..1 -> 128 rows
  const int wn   = wave & 3;        // 0..3 -> 96 cols
  const int l31  = lane & 31;
  const int kHi  = (lane >> 5) * 8;

  // XCD-aware bijective swizzle: 400 = 8 * 50; same-slice blocks adjacent
  const int bid   = blockIdx.x;
  const int swz   = (bid & 7) * 50 + (bid >> 3);
  const int slice = swz >> 2;       // 0..99
  const int mt    = swz & 3;        // 0..3

  const float* xbase = x    + (size_t)mt * BM * XROW + (size_t)slice * DIN;
  const float* wbase = w    + (size_t)slice * WSLICE;
  const float* bbase = bias + (size_t)slice * DOUT;
  float*       obase = out  + (size_t)mt * BM * XROW + (size_t)slice * DOUT;

  // A staging (R6-proven): 4 float4/thread, lanes 0..7 = one 128B row chunk
  const int a_c4 = tid & 7;
  const int a_r0 = tid >> 3;        // 0..63, rows +64*i

  unsigned au[4][2];
  unsigned bu[6][2];

  auto G2R = [&](int k0) {
#pragma unroll
    for (int i = 0; i < 4; ++i) {
      const float4 v = *reinterpret_cast<const float4*>(
          xbase + (size_t)(a_r0 + 64 * i) * XROW + k0 + a_c4 * 4);
      au[i][0] = pack2(v.x, v.y);
      au[i][1] = pack2(v.z, v.w);
    }
    // B: flat cover of [32k][96 o-quads]; consecutive tid -> consecutive o4
#pragma unroll
    for (int j = 0; j < 6; ++j) {
      const int f4i = tid + 512 * j;      // 0..3071
      const int bk  = f4i / 96;
      const int bo  = f4i - bk * 96;
      const float4 v = *reinterpret_cast<const float4*>(
          wbase + (size_t)(k0 + bk) * DOUT + bo * 4);
      bu[j][0] = pack2(v.x, v.y);
      bu[j][1] = pack2(v.z, v.w);
    }
  };

  auto R2L = [&](int buf) {
    short* A = lA + buf * ASZ;
    short* B = lB + buf * BSZ;
#pragma unroll
    for (int i = 0; i < 4; ++i)
      *reinterpret_cast<uint2*>(&A[(a_r0 + 64 * i) * PA + a_c4 * 4]) =
          uint2{au[i][0], au[i][1]};
#pragma unroll
    for (int j = 0; j < 6; ++j) {
      const int f4i = tid + 512 * j;
      const int bk  = f4i / 96;
      const int bo  = f4i - bk * 96;
      *reinterpret_cast<uint2*>(&B[bk * PBT + bo * 4]) =
          uint2{bu[j][0], bu[j][1]};
    }
  };

  f32x16 acc[4][3];
#pragma unroll
  for (int mi = 0; mi < 4; ++mi)
#pragma unroll
    for (int ni = 0; ni < 3; ++ni)
#pragma unroll
      for (int q = 0; q < 16; ++q)
        acc[mi][ni][q] = 0.f;

  G2R(0);
  R2L(0);
  barrier_nodrain();
  G2R(BK);

  auto STEP = [&](int ks, int cb) {
    if (ks + 1 < NK) R2L(cb ^ 1);
    if (ks + 2 < NK) G2R((ks + 2) * BK);
    const short* A = lA + cb * ASZ;
    const short* B = lB + cb * BSZ;
    // kk-outer keeps live fragments small (VGPR budget)
#pragma unroll
    for (int kk = 0; kk < 2; ++kk) {
      bf16x8 af[4];
#pragma unroll
      for (int mi = 0; mi < 4; ++mi)
        af[mi] = *reinterpret_cast<const bf16x8*>(
            &A[(wm * 128 + mi * 32 + l31) * PA + kk * 16 + kHi]);
      bf16x8 bfv[3];
#pragma unroll
      for (int ni = 0; ni < 3; ++ni) {
        const int col = wn * 96 + ni * 32 + l31;
#pragma unroll
        for (int j = 0; j < 8; ++j)
          bfv[ni][j] = B[(kk * 16 + kHi + j) * PBT + col];   // R3-validated
      }
#pragma unroll
      for (int mi = 0; mi < 4; ++mi)
#pragma unroll
        for (int ni = 0; ni < 3; ++ni)
          acc[mi][ni] = __builtin_amdgcn_mfma_f32_32x32x16_bf16(
              af[mi], bfv[ni], acc[mi][ni], 0, 0, 0);
    }
    barrier_nodrain();
  };

#pragma unroll
  for (int ks = 0; ks < NK; ks += 2) {
    STEP(ks, 0);
    STEP(ks + 1, 1);
  }

  // Epilogue. 32x32 D frag: col = lane&31, row = (q&3) + 8*(q>>2) + 4*(lane>>5)
  float bv[3];
#pragma unroll
  for (int ni = 0; ni < 3; ++ni) bv[ni] = bbase[wn * 96 + ni * 32 + l31];

  const int rsub = ((lane >> 5) << 2);
#pragma unroll
  for (int mi = 0; mi < 4; ++mi) {
#pragma unroll
    for (int ni = 0; ni < 3; ++ni) {
      const int c = wn * 96 + ni * 32 + l31;
#pragma unroll
      for (int q = 0; q < 16; ++q) {
        const int row = wm * 128 + mi * 32 + rsub + (q & 3) + 8 * (q >> 2);
        obase[(size_t)row * XROW + c] = acc[mi][ni][q] + bv[ni];
      }
    }
  }
}

extern "C" void kernel_launch(void* const* d_in, const int* in_sizes, int n_in,
                              void* d_out, int out_size, void* d_ws, size_t ws_size,
                              hipStream_t stream) {
  const float* x  = (const float*)d_in[0];
  const float* w  = (const float*)d_in[1];
  const float* b  = (const float*)d_in[2];
  float* out      = (float*)d_out;
  hipFuncSetAttribute((const void*)nlinear_kernel,
                      hipFuncAttributeMaxDynamicSharedMemorySize, LDS_BYTES);
  const int grid = NPOS * (BATCH / BM);   // 400
  nlinear_kernel<<<grid, 512, LDS_BYTES, stream>>>(x, w, b, out);
}

// Round 11
// 292.051 us; speedup vs baseline: 1.8761x; 1.8761x over previous
//
#include <hip/hip_runtime.h>
#include <hip/hip_bf16.h>

#define NPOS   100
#define BATCH  1024
#define DIN    384
#define DOUT   384
#define XROW   (NPOS * DIN)      // 38400 floats, batch-dim stride of x and out
#define WSLICE (DIN * DOUT)

#define BM 128
#define BN 192                   // x read 2x (was 3x at BN=128)
#define BK 32
#define NK (DIN / BK)            // 12 K-steps
#define PA 40                    // A pitch (shorts): 80B rows (R6-proven)
#define PBT 200                  // B natural [k][o] pitch (shorts): 400B rows
#define NQ (BN / 4)              // 48 o-quads per k-row

typedef __attribute__((ext_vector_type(8))) short bf16x8;
typedef __attribute__((ext_vector_type(16))) float f32x16;

__device__ __forceinline__ unsigned f2bfu(float f) {
  return (unsigned)__builtin_bit_cast(unsigned short, __float2bfloat16(f));
}
__device__ __forceinline__ unsigned pack2(float a, float b) {
  return f2bfu(a) | (f2bfu(b) << 16);
}

// ds ops visible, vmcnt NOT drained (global prefetch survives the barrier)
__device__ __forceinline__ void barrier_nodrain() {
  asm volatile("s_waitcnt lgkmcnt(0)" ::: "memory");
  __builtin_amdgcn_s_barrier();
}

__global__ __launch_bounds__(256, 3) void nlinear_kernel(
    const float* __restrict__ x, const float* __restrict__ w,
    const float* __restrict__ bias, float* __restrict__ out)
{
  __shared__ short lA[2][BM * PA];    // [b-row][k]  10.0 KiB x2
  __shared__ short lB[2][BK * PBT];   // [k][o] nat. 12.5 KiB x2 -> 46,080 B

  const int tid  = threadIdx.x;
  const int lane = tid & 63;
  const int wave = tid >> 6;          // 4 waves: 2m x 2n
  const int wm   = wave >> 1;         // 0..1 -> 64 rows
  const int wn   = wave & 1;          // 0..1 -> 96 cols
  const int l31  = lane & 31;
  const int kHi  = (lane >> 5) * 8;

  // XCD-aware bijective swizzle: 1600 = 8 * 200.
  // Order (slice, mt, nt): nt-pair of same x-tile adjacent on one XCD.
  const int bid   = blockIdx.x;
  const int swz   = (bid & 7) * 200 + (bid >> 3);
  const int slice = swz >> 4;         // 0..99
  const int rem   = swz & 15;
  const int mt    = rem >> 1;         // 0..7
  const int nt    = rem & 1;          // 0..1

  const float* xbase = x    + (size_t)mt * BM * XROW + (size_t)slice * DIN;
  const float* wbase = w    + (size_t)slice * WSLICE + nt * BN;
  const float* bbase = bias + (size_t)slice * DOUT   + nt * BN;
  float*       obase = out  + (size_t)mt * BM * XROW + (size_t)slice * DOUT + nt * BN;

  // A staging (R6-exact): 4 float4/thread, lanes 0..7 = one 128B row chunk
  const int a_c4   = tid & 7;
  const int a_row0 = tid >> 3;        // 0..31, rows +32i

  unsigned au[4][2];
  unsigned bu[6][2];

  auto G2R = [&](int k0) {
#pragma unroll
    for (int i = 0; i < 4; ++i) {
      const float4 v = *reinterpret_cast<const float4*>(
          xbase + (size_t)(a_row0 + 32 * i) * XROW + k0 + a_c4 * 4);
      au[i][0] = pack2(v.x, v.y);
      au[i][1] = pack2(v.z, v.w);
    }
    // B: flat cover of [32k][48 o-quads]; consecutive tid -> consecutive o4
#pragma unroll
    for (int j = 0; j < 6; ++j) {
      const int f4i = tid + 256 * j;        // 0..1535
      const int bk  = f4i / NQ;
      const int bo  = f4i - bk * NQ;
      const float4 v = *reinterpret_cast<const float4*>(
          wbase + (size_t)(k0 + bk) * DOUT + bo * 4);
      bu[j][0] = pack2(v.x, v.y);
      bu[j][1] = pack2(v.z, v.w);
    }
  };

  auto R2L = [&](int buf) {
#pragma unroll
    for (int i = 0; i < 4; ++i)
      *reinterpret_cast<uint2*>(&lA[buf][(a_row0 + 32 * i) * PA + a_c4 * 4]) =
          uint2{au[i][0], au[i][1]};
#pragma unroll
    for (int j = 0; j < 6; ++j) {
      const int f4i = tid + 256 * j;
      const int bk  = f4i / NQ;
      const int bo  = f4i - bk * NQ;
      *reinterpret_cast<uint2*>(&lB[buf][bk * PBT + bo * 4]) =
          uint2{bu[j][0], bu[j][1]};
    }
  };

  f32x16 acc[2][3];
#pragma unroll
  for (int m = 0; m < 2; ++m)
#pragma unroll
    for (int n = 0; n < 3; ++n)
#pragma unroll
      for (int q = 0; q < 16; ++q)
        acc[m][n][q] = 0.f;

  G2R(0);
  R2L(0);
  barrier_nodrain();
  G2R(BK);

  auto STEP = [&](int ks, int cb) {
    if (ks + 1 < NK) R2L(cb ^ 1);
    if (ks + 2 < NK) G2R((ks + 2) * BK);
    // kk-outer: caps live fragments (VGPR control — R10 lesson)
#pragma unroll
    for (int kk = 0; kk < 2; ++kk) {
      bf16x8 af[2];
#pragma unroll
      for (int m = 0; m < 2; ++m)
        af[m] = *reinterpret_cast<const bf16x8*>(
            &lA[cb][(wm * 64 + m * 32 + l31) * PA + kk * 16 + kHi]);
      bf16x8 bfv[3];
#pragma unroll
      for (int n = 0; n < 3; ++n) {
        const int col = wn * 96 + n * 32 + l31;
#pragma unroll
        for (int j = 0; j < 8; ++j)
          bfv[n][j] = lB[cb][(kk * 16 + kHi + j) * PBT + col];  // R3-validated
      }
#pragma unroll
      for (int m = 0; m < 2; ++m)
#pragma unroll
        for (int n = 0; n < 3; ++n)
          acc[m][n] = __builtin_amdgcn_mfma_f32_32x32x16_bf16(
              af[m], bfv[n], acc[m][n], 0, 0, 0);
    }
    barrier_nodrain();
  };

#pragma unroll
  for (int ks = 0; ks < NK; ks += 2) {
    STEP(ks, 0);
    STEP(ks + 1, 1);
  }

  // Epilogue. 32x32 D frag: col = lane&31, row = (q&3) + 8*(q>>2) + 4*(lane>>5)
  float bv[3];
#pragma unroll
  for (int n = 0; n < 3; ++n) bv[n] = bbase[wn * 96 + n * 32 + l31];

  const int rbase = wm * 64 + ((lane >> 5) << 2);
#pragma unroll
  for (int m = 0; m < 2; ++m) {
#pragma unroll
    for (int n = 0; n < 3; ++n) {
      const int c = wn * 96 + n * 32 + l31;
#pragma unroll
      for (int q = 0; q < 16; ++q) {
        const int row = rbase + m * 32 + (q & 3) + 8 * (q >> 2);
        obase[(size_t)row * XROW + c] = acc[m][n][q] + bv[n];
      }
    }
  }
}

extern "C" void kernel_launch(void* const* d_in, const int* in_sizes, int n_in,
                              void* d_out, int out_size, void* d_ws, size_t ws_size,
                              hipStream_t stream) {
  const float* x  = (const float*)d_in[0];
  const float* w  = (const float*)d_in[1];
  const float* b  = (const float*)d_in[2];
  float* out      = (float*)d_out;
  const int grid  = NPOS * (BATCH / BM) * (DOUT / BN);  // 1600
  nlinear_kernel<<<grid, 256, 0, stream>>>(x, w, b, out);
}